// Round 1
// baseline (1532.005 us; speedup 1.0000x reference)
//
#include <hip/hip_runtime.h>

#define CIN   256
#define NTOK  16384
#define NHEAD 8

// workspace float offsets (total 788480 floats ~ 3.08 MB)
#define WT_OFF   0        // 256*768 transposed w_qkv
#define CTX_OFF  196608   // 8*8*32*32 context numerator (atomic-accumulated)
#define Z_OFF    262144   // 8*8*32 softmax-k denominators
#define MT_OFF   264192   // 8*256*256 fused (w_out * context) matrices, transposed

__global__ void transpose_wqkv_k(const float* __restrict__ w, float* __restrict__ wt)
{
    const int c = blockIdx.x;                 // 0..255
    for (int o = threadIdx.x; o < 768; o += 256)
        wt[c * 768 + o] = w[o * 256 + c];
}

// K_A: compute k,v for 32-token chunks, exp(k), accumulate per-head outer products
// into global ctx numerator + z sums via atomics. GEMM operands straight from
// global (L2-resident weights); LDS holds only the [32 tok][512 ch] exp(k)/v tile.
__launch_bounds__(256, 2)
__global__ void kv_context_k(const float* __restrict__ x,
                             const float* __restrict__ wt,
                             const float* __restrict__ bqkv,
                             float* __restrict__ ctxn,
                             float* __restrict__ zsum)
{
    __shared__ float kv[32 * 512];            // 64 KB: [token][channel]
    const int tid  = threadIdx.x;
    const int b    = blockIdx.x >> 6;         // 8 batches
    const int tile = blockIdx.x & 63;         // 64 tiles * 256 tokens
    const int cg   = tid >> 2;                // 0..63 -> 8 kv channels each
    const int t0   = (tid & 3) << 3;          // 0,8,16,24 -> 8 tokens each
    const float* xb = x + (size_t)b * CIN * NTOK;

    float bias[8];
#pragma unroll
    for (int i = 0; i < 8; ++i) bias[i] = bqkv[256 + cg * 8 + i];

    // phase-3 (outer product) mapping: one thread owns (head, 4 c, 8 d)
    const int h  = tid >> 5;                  // 0..7
    const int s  = tid & 31;
    const int c0 = (s >> 2) << 2;             // 0,4,...,28
    const int d0 = (s & 3) << 3;              // 0,8,16,24

    float ctxa[4][8];
#pragma unroll
    for (int a = 0; a < 4; ++a)
#pragma unroll
        for (int e = 0; e < 8; ++e) ctxa[a][e] = 0.f;
    float za[4] = {0.f, 0.f, 0.f, 0.f};

    for (int chunk = 0; chunk < 8; ++chunk) {
        const int n0 = tile * 256 + chunk * 32;

        float acc[8][8];
#pragma unroll
        for (int i = 0; i < 8; ++i)
#pragma unroll
            for (int j = 0; j < 8; ++j) acc[i][j] = 0.f;

        for (int kb = 0; kb < 256; kb += 16) {
#pragma unroll
            for (int k = 0; k < 16; ++k) {
                const float* wr = wt + (kb + k) * 768 + 256 + cg * 8;
                const float4 a0 = *(const float4*)(wr);
                const float4 a1 = *(const float4*)(wr + 4);
                const float* xr = xb + (size_t)(kb + k) * NTOK + n0 + t0;
                const float4 b0 = *(const float4*)(xr);
                const float4 b1 = *(const float4*)(xr + 4);
                const float av[8] = {a0.x, a0.y, a0.z, a0.w, a1.x, a1.y, a1.z, a1.w};
                const float bv[8] = {b0.x, b0.y, b0.z, b0.w, b1.x, b1.y, b1.z, b1.w};
#pragma unroll
                for (int i = 0; i < 8; ++i)
#pragma unroll
                    for (int j = 0; j < 8; ++j)
                        acc[i][j] += av[i] * bv[j];
            }
        }

        __syncthreads();   // previous chunk's phase-3 readers done
        if (cg < 32) {     // k channels: store exp(k + bias)
#pragma unroll
            for (int j = 0; j < 8; ++j) {
                float4 w0, w1;
                w0.x = __expf(acc[0][j] + bias[0]);
                w0.y = __expf(acc[1][j] + bias[1]);
                w0.z = __expf(acc[2][j] + bias[2]);
                w0.w = __expf(acc[3][j] + bias[3]);
                w1.x = __expf(acc[4][j] + bias[4]);
                w1.y = __expf(acc[5][j] + bias[5]);
                w1.z = __expf(acc[6][j] + bias[6]);
                w1.w = __expf(acc[7][j] + bias[7]);
                float* dst = &kv[(t0 + j) * 512 + cg * 8];
                *(float4*)dst = w0;
                *(float4*)(dst + 4) = w1;
            }
        } else {           // v channels: store v + bias
#pragma unroll
            for (int j = 0; j < 8; ++j) {
                const float4 w0 = make_float4(acc[0][j] + bias[0], acc[1][j] + bias[1],
                                              acc[2][j] + bias[2], acc[3][j] + bias[3]);
                const float4 w1 = make_float4(acc[4][j] + bias[4], acc[5][j] + bias[5],
                                              acc[6][j] + bias[6], acc[7][j] + bias[7]);
                float* dst = &kv[(t0 + j) * 512 + cg * 8];
                *(float4*)dst = w0;
                *(float4*)(dst + 4) = w1;
            }
        }
        __syncthreads();

        // phase 3: ctx[h][c][d] += exp(k[h,c,t]) * v[h,d,t]
#pragma unroll 4
        for (int t = 0; t < 32; ++t) {
            const float* row = &kv[t * 512];
            const float4 ek = *(const float4*)(row + h * 32 + c0);
            const float4 v0 = *(const float4*)(row + 256 + h * 32 + d0);
            const float4 v1 = *(const float4*)(row + 256 + h * 32 + d0 + 4);
            const float ekv[4] = {ek.x, ek.y, ek.z, ek.w};
            const float vv[8]  = {v0.x, v0.y, v0.z, v0.w, v1.x, v1.y, v1.z, v1.w};
            if (d0 == 0) {
#pragma unroll
                for (int a = 0; a < 4; ++a) za[a] += ekv[a];
            }
#pragma unroll
            for (int a = 0; a < 4; ++a)
#pragma unroll
                for (int e = 0; e < 8; ++e)
                    ctxa[a][e] += ekv[a] * vv[e];
        }
    }

    float* cp = ctxn + ((size_t)(b * NHEAD + h) * 32) * 32;
#pragma unroll
    for (int a = 0; a < 4; ++a)
#pragma unroll
        for (int e = 0; e < 8; ++e)
            atomicAdd(&cp[(c0 + a) * 32 + d0 + e], ctxa[a][e]);
    if (d0 == 0) {
#pragma unroll
        for (int a = 0; a < 4; ++a)
            atomicAdd(&zsum[(b * NHEAD + h) * 32 + c0 + a], za[a]);
    }
}

// K_B: Mt[b][h*32+c][o] = sum_d w_out[o][h*32+d] * (ctxn[b,h,c,d] / z[b,h,c])
__global__ void build_m_k(const float* __restrict__ ctxn,
                          const float* __restrict__ zsum,
                          const float* __restrict__ wout,
                          float* __restrict__ mt)
{
    __shared__ float cl[1024];
    __shared__ float zl[32];
    const int b = blockIdx.x >> 3;
    const int h = blockIdx.x & 7;
    const int tid = threadIdx.x;
    if (tid < 32) zl[tid] = 1.0f / zsum[(b * 8 + h) * 32 + tid];
    __syncthreads();
    for (int i = tid; i < 1024; i += 256)
        cl[i] = ctxn[((size_t)(b * 8 + h) * 32) * 32 + i] * zl[i >> 5];
    __syncthreads();
    const int o = tid;
    float wrow[32];
#pragma unroll
    for (int d = 0; d < 32; ++d) wrow[d] = wout[o * 256 + h * 32 + d];
#pragma unroll 4
    for (int c = 0; c < 32; ++c) {
        float m = 0.f;
#pragma unroll
        for (int d = 0; d < 32; ++d) m += wrow[d] * cl[c * 32 + d];
        mt[((size_t)b * 256 + h * 32 + c) * 256 + o] = m;
    }
}

// K_C: per 64-token tile: q = Wq@x (+bias) -> LDS -> per-head channel softmax
//      -> out = M_b @ q_s + b_out
__launch_bounds__(256, 2)
__global__ void final_k(const float* __restrict__ x,
                        const float* __restrict__ wt,
                        const float* __restrict__ bqkv,
                        const float* __restrict__ mt,
                        const float* __restrict__ bout,
                        float* __restrict__ out)
{
    __shared__ float qs[256 * 64];            // 64 KB: [q channel][token]
    const int tid  = threadIdx.x;
    const int b    = blockIdx.x >> 8;
    const int tile = blockIdx.x & 255;
    const int n0   = tile * 64;
    const int cg   = tid >> 3;                // 0..31 -> 8 channels
    const int t0   = (tid & 7) << 3;          // 0..56 -> 8 tokens
    const float* xb = x + (size_t)b * CIN * NTOK;

    float acc[8][8];
#pragma unroll
    for (int i = 0; i < 8; ++i)
#pragma unroll
        for (int j = 0; j < 8; ++j) acc[i][j] = 0.f;

    // GEMM1: qraw[256][64]
    for (int kb = 0; kb < 256; kb += 16) {
#pragma unroll
        for (int k = 0; k < 16; ++k) {
            const float* wr = wt + (kb + k) * 768 + cg * 8;
            const float4 a0 = *(const float4*)(wr);
            const float4 a1 = *(const float4*)(wr + 4);
            const float* xr = xb + (size_t)(kb + k) * NTOK + n0 + t0;
            const float4 b0 = *(const float4*)(xr);
            const float4 b1 = *(const float4*)(xr + 4);
            const float av[8] = {a0.x, a0.y, a0.z, a0.w, a1.x, a1.y, a1.z, a1.w};
            const float bv[8] = {b0.x, b0.y, b0.z, b0.w, b1.x, b1.y, b1.z, b1.w};
#pragma unroll
            for (int i = 0; i < 8; ++i)
#pragma unroll
                for (int j = 0; j < 8; ++j)
                    acc[i][j] += av[i] * bv[j];
        }
    }
    {
        float bq[8];
#pragma unroll
        for (int i = 0; i < 8; ++i) bq[i] = bqkv[cg * 8 + i];
#pragma unroll
        for (int i = 0; i < 8; ++i) {
            const float4 w0 = make_float4(acc[i][0] + bq[i], acc[i][1] + bq[i],
                                          acc[i][2] + bq[i], acc[i][3] + bq[i]);
            const float4 w1 = make_float4(acc[i][4] + bq[i], acc[i][5] + bq[i],
                                          acc[i][6] + bq[i], acc[i][7] + bq[i]);
            float* dst = &qs[(cg * 8 + i) * 64 + t0];
            *(float4*)dst = w0;
            *(float4*)(dst + 4) = w1;
        }
    }
    __syncthreads();

    // softmax over the 32 channels of each head (no max-sub: |q| small, fp32-safe)
    for (int rep = 0; rep < 2; ++rep) {
        const int hh = (tid >> 6) + (rep << 2);
        const int t  = tid & 63;
        float e[32];
        float ssum = 0.f;
#pragma unroll
        for (int c = 0; c < 32; ++c) {
            e[c] = __expf(qs[(hh * 32 + c) * 64 + t]);
            ssum += e[c];
        }
        const float r = 1.0f / ssum;
#pragma unroll
        for (int c = 0; c < 32; ++c)
            qs[(hh * 32 + c) * 64 + t] = e[c] * r;
    }
    __syncthreads();

    // GEMM2: out[o][t] = sum_cq Mt[cq][o] * qs[cq][t]
#pragma unroll
    for (int i = 0; i < 8; ++i)
#pragma unroll
        for (int j = 0; j < 8; ++j) acc[i][j] = 0.f;
    const float* mtb = mt + (size_t)b * 65536;
    for (int kb = 0; kb < 256; kb += 16) {
#pragma unroll
        for (int k = 0; k < 16; ++k) {
            const float* mr = mtb + (kb + k) * 256 + cg * 8;
            const float4 a0 = *(const float4*)(mr);
            const float4 a1 = *(const float4*)(mr + 4);
            const float* qr = &qs[(kb + k) * 64 + t0];
            const float4 b0 = *(const float4*)(qr);
            const float4 b1 = *(const float4*)(qr + 4);
            const float av[8] = {a0.x, a0.y, a0.z, a0.w, a1.x, a1.y, a1.z, a1.w};
            const float bv[8] = {b0.x, b0.y, b0.z, b0.w, b1.x, b1.y, b1.z, b1.w};
#pragma unroll
            for (int i = 0; i < 8; ++i)
#pragma unroll
                for (int j = 0; j < 8; ++j)
                    acc[i][j] += av[i] * bv[j];
        }
    }

    float bo[8];
#pragma unroll
    for (int i = 0; i < 8; ++i) bo[i] = bout[cg * 8 + i];
    float* ob = out + (size_t)b * CIN * NTOK;
#pragma unroll
    for (int i = 0; i < 8; ++i) {
        const int o = cg * 8 + i;
        const float4 s0 = make_float4(acc[i][0] + bo[i], acc[i][1] + bo[i],
                                      acc[i][2] + bo[i], acc[i][3] + bo[i]);
        const float4 s1 = make_float4(acc[i][4] + bo[i], acc[i][5] + bo[i],
                                      acc[i][6] + bo[i], acc[i][7] + bo[i]);
        float* op = ob + (size_t)o * NTOK + n0 + t0;
        *(float4*)op = s0;
        *(float4*)(op + 4) = s1;
    }
}

extern "C" void kernel_launch(void* const* d_in, const int* in_sizes, int n_in,
                              void* d_out, int out_size, void* d_ws, size_t ws_size,
                              hipStream_t stream)
{
    (void)in_sizes; (void)n_in; (void)out_size; (void)ws_size;
    const float* x    = (const float*)d_in[0];
    const float* wqkv = (const float*)d_in[1];
    const float* bqkv = (const float*)d_in[2];
    const float* wout = (const float*)d_in[3];
    const float* bout = (const float*)d_in[4];
    float* out = (float*)d_out;
    float* ws  = (float*)d_ws;

    float* wt   = ws + WT_OFF;
    float* ctxn = ws + CTX_OFF;
    float* zsum = ws + Z_OFF;
    float* mt   = ws + MT_OFF;

    hipMemsetAsync(ctxn, 0, (65536 + 2048) * sizeof(float), stream);
    transpose_wqkv_k<<<256, 256, 0, stream>>>(wqkv, wt);
    kv_context_k<<<512, 256, 0, stream>>>(x, wt, bqkv, ctxn, zsum);
    build_m_k<<<64, 256, 0, stream>>>(ctxn, zsum, wout, mt);
    final_k<<<2048, 256, 0, stream>>>(x, wt, bqkv, mt, bout, out);
}

// Round 2
// 554.975 us; speedup vs baseline: 2.7605x; 2.7605x over previous
//
#include <hip/hip_runtime.h>

#define NTOK 16384

typedef short           bf16x8 __attribute__((ext_vector_type(8)));
typedef float           f32x4  __attribute__((ext_vector_type(4)));
typedef unsigned short  u16x4  __attribute__((ext_vector_type(4)));

// ws float offsets (total 788480 floats ~= 3.08 MB, same footprint as passing R1)
#define WHI_OFF 0         // 768*256 ushort  (98304 floats)
#define WLO_OFF 98304     // 768*256 ushort
#define CTX_OFF 196608    // 65536 floats (atomic ctx numerator)
#define Z_OFF   262144    // 2048 floats  (atomic z sums)
#define MHI_OFF 264192    // 8*256*256 ushort (262144 floats)
#define MLO_OFF 526336    // 8*256*256 ushort

union UB8 { unsigned u[4]; bf16x8 v; };

// split fp32 pair into packed hi-bf16 pair and lo-bf16 pair (truncation split;
// residual after hi+lo is ~2^-17 relative — covered by the 3-product MFMA scheme)
__device__ __forceinline__ void split2(float v0, float v1, unsigned& hi, unsigned& lo) {
    unsigned b0 = __float_as_uint(v0), b1 = __float_as_uint(v1);
    unsigned h0 = b0 & 0xffff0000u, h1 = b1 & 0xffff0000u;
    hi = (b0 >> 16) | h1;
    float r0 = v0 - __uint_as_float(h0);
    float r1 = v1 - __uint_as_float(h1);
    lo = (__float_as_uint(r0) >> 16) | (__float_as_uint(r1) & 0xffff0000u);
}

__device__ __forceinline__ unsigned short bf16_trunc(float v) {
    return (unsigned short)(__float_as_uint(v) >> 16);
}
__device__ __forceinline__ float bf16_f(unsigned short u) {
    return __uint_as_float(((unsigned)u) << 16);
}

// prep: split w_qkv [768][256] fp32 -> whi/wlo bf16 planes (A-operand layout, k-contiguous)
__global__ void splitw_k(const float* __restrict__ w,
                         unsigned short* __restrict__ whi,
                         unsigned short* __restrict__ wlo)
{
    const int gid = blockIdx.x * 256 + threadIdx.x;   // 24576 threads x 8 elems
    const float4* wp = (const float4*)w;
    float4 a = wp[gid * 2], b = wp[gid * 2 + 1];
    unsigned h0, h1, h2, h3, l0, l1, l2, l3;
    split2(a.x, a.y, h0, l0);
    split2(a.z, a.w, h1, l1);
    split2(b.x, b.y, h2, l2);
    split2(b.z, b.w, h3, l3);
    ((uint4*)whi)[gid] = make_uint4(h0, h1, h2, h3);
    ((uint4*)wlo)[gid] = make_uint4(l0, l1, l2, l3);
}

// K_A: per block: 256 tokens (4 chunks of 64). Per chunk:
//   MFMA GEMM kv[512][64] (split-3 bf16), epilogue bias(+exp for k) -> bf16 LDS
//   tile kvt[tok][512ch] with ch XOR-swizzle ((t&7)<<3), then per-head context
//   GEMM ctx[32][32] += ek . v^T via single-product bf16 MFMA. Atomic flush at end.
__launch_bounds__(256, 2)
__global__ void kv_ctx_k(const float* __restrict__ x,
                         const unsigned short* __restrict__ whi,
                         const unsigned short* __restrict__ wlo,
                         const float* __restrict__ bqkv,
                         float* __restrict__ ctxn, float* __restrict__ zsum)
{
    __shared__ unsigned short kvt[32768];   // 64 KB: [tok 64][ch 512] swizzled
    const int tid  = threadIdx.x;
    const int wave = tid >> 6, lane = tid & 63;
    const int quad = lane >> 4, l16 = lane & 15;
    const int b = blockIdx.x >> 6, tile = blockIdx.x & 63;
    const float* xb = x + (size_t)b * 256 * NTOK;

    // persistent context accumulators: wave owns heads 2w, 2w+1
    f32x4 cacc[2][2][2];
#pragma unroll
    for (int a0 = 0; a0 < 2; ++a0)
#pragma unroll
        for (int a1 = 0; a1 < 2; ++a1)
#pragma unroll
            for (int a2 = 0; a2 < 2; ++a2)
                cacc[a0][a1][a2] = (f32x4){0.f, 0.f, 0.f, 0.f};
    float zacc = 0.f;
    const int zh = tid >> 5, zc = tid & 31;

    for (int chunk = 0; chunk < 4; ++chunk) {
        const int n0 = tile * 256 + chunk * 64;

        for (int half = 0; half < 2; ++half) {          // half0 = k rows, half1 = v rows
            f32x4 acc[4][4];
#pragma unroll
            for (int rt = 0; rt < 4; ++rt)
#pragma unroll
                for (int ct = 0; ct < 4; ++ct) acc[rt][ct] = (f32x4){0.f, 0.f, 0.f, 0.f};

            const int rowbase = 256 + half * 256 + wave * 64;

            for (int k0 = 0; k0 < 256; k0 += 32) {
                bf16x8 ah[4], al[4];
#pragma unroll
                for (int rt = 0; rt < 4; ++rt) {
                    const int off = (rowbase + rt * 16 + l16) * 256 + k0 + quad * 8;
                    ah[rt] = *(const bf16x8*)(whi + off);
                    al[rt] = *(const bf16x8*)(wlo + off);
                }
                bf16x8 bh[4], bl[4];
#pragma unroll
                for (int ct = 0; ct < 4; ++ct) {
                    const float* xp = xb + (size_t)(k0 + quad * 8) * NTOK + n0 + ct * 16 + l16;
                    UB8 hu, lu;
#pragma unroll
                    for (int p = 0; p < 4; ++p) {
                        float v0 = xp[(2 * p) * NTOK];
                        float v1 = xp[(2 * p + 1) * NTOK];
                        split2(v0, v1, hu.u[p], lu.u[p]);
                    }
                    bh[ct] = hu.v; bl[ct] = lu.v;
                }
#pragma unroll
                for (int rt = 0; rt < 4; ++rt)
#pragma unroll
                    for (int ct = 0; ct < 4; ++ct) {
                        acc[rt][ct] = __builtin_amdgcn_mfma_f32_16x16x32_bf16(ah[rt], bh[ct], acc[rt][ct], 0, 0, 0);
                        acc[rt][ct] = __builtin_amdgcn_mfma_f32_16x16x32_bf16(al[rt], bh[ct], acc[rt][ct], 0, 0, 0);
                        acc[rt][ct] = __builtin_amdgcn_mfma_f32_16x16x32_bf16(ah[rt], bl[ct], acc[rt][ct], 0, 0, 0);
                    }
            }
            // epilogue: bias (+exp on k half), truncate to bf16, swizzled LDS store
#pragma unroll
            for (int rt = 0; rt < 4; ++rt)
#pragma unroll
                for (int ct = 0; ct < 4; ++ct) {
                    const int t   = ct * 16 + l16;
                    const int s   = (t & 7) << 3;
                    const int ch0 = half * 256 + wave * 64 + rt * 16 + quad * 4;
                    u16x4 st;
#pragma unroll
                    for (int r = 0; r < 4; ++r) {
                        float val = acc[rt][ct][r] + bqkv[256 + ch0 + r];
                        if (half == 0) val = __expf(val);
                        st[r] = bf16_trunc(val);
                    }
                    *(u16x4*)&kvt[t * 512 + (ch0 ^ s)] = st;
                }
        }
        __syncthreads();   // kv tile complete

        // phase 3: ctx[h][c][d] += sum_t ek[c,t]*v[d,t]  (MFMA, A=ek[c][t], B=v[t][d])
#pragma unroll
        for (int hh = 0; hh < 2; ++hh) {
            const int h = wave * 2 + hh;
#pragma unroll
            for (int ks = 0; ks < 2; ++ks) {
                bf16x8 af[2], bf[2];
#pragma unroll
                for (int mi = 0; mi < 2; ++mi)
#pragma unroll
                    for (int j = 0; j < 8; ++j) {
                        const int t = ks * 32 + quad * 8 + j;
                        af[mi][j] = (short)kvt[t * 512 + ((h * 32 + mi * 16 + l16) ^ (j << 3))];
                    }
#pragma unroll
                for (int ni = 0; ni < 2; ++ni)
#pragma unroll
                    for (int j = 0; j < 8; ++j) {
                        const int t = ks * 32 + quad * 8 + j;
                        bf[ni][j] = (short)kvt[t * 512 + ((256 + h * 32 + ni * 16 + l16) ^ (j << 3))];
                    }
#pragma unroll
                for (int mi = 0; mi < 2; ++mi)
#pragma unroll
                    for (int ni = 0; ni < 2; ++ni)
                        cacc[hh][mi][ni] = __builtin_amdgcn_mfma_f32_16x16x32_bf16(af[mi], bf[ni], cacc[hh][mi][ni], 0, 0, 0);
            }
        }
        // z sums (same bf16-rounded ek as the numerator -> consistent ratio)
#pragma unroll 8
        for (int t = 0; t < 64; ++t)
            zacc += bf16_f(kvt[t * 512 + ((zh * 32 + zc) ^ ((t & 7) << 3))]);
        __syncthreads();   // phase-3 reads done before next chunk's epilogue writes
    }

    // flush
#pragma unroll
    for (int hh = 0; hh < 2; ++hh) {
        const int h = wave * 2 + hh;
        float* cp = ctxn + ((size_t)(b * 8 + h)) * 1024;
#pragma unroll
        for (int mi = 0; mi < 2; ++mi)
#pragma unroll
            for (int ni = 0; ni < 2; ++ni)
#pragma unroll
                for (int r = 0; r < 4; ++r) {
                    const int c = mi * 16 + quad * 4 + r;
                    const int d = ni * 16 + l16;
                    atomicAdd(&cp[c * 32 + d], cacc[hh][mi][ni][r]);
                }
    }
    atomicAdd(&zsum[(b * 8 + zh) * 32 + zc], zacc);
}

// K_B: M[b][o][ch=h*32+c] = sum_d w_out[o][h*32+d] * (ctxn[b,h,c,d]/z[b,h,c]) -> hi/lo bf16
__global__ void build_m_k(const float* __restrict__ ctxn, const float* __restrict__ zsum,
                          const float* __restrict__ wout,
                          unsigned short* __restrict__ mhi, unsigned short* __restrict__ mlo)
{
    __shared__ float cl[1024];
    __shared__ float zl[32];
    const int b = blockIdx.x >> 3, h = blockIdx.x & 7;
    const int tid = threadIdx.x;
    if (tid < 32) zl[tid] = 1.0f / zsum[(b * 8 + h) * 32 + tid];
    __syncthreads();
    for (int i = tid; i < 1024; i += 256)
        cl[i] = ctxn[(size_t)(b * 8 + h) * 1024 + i] * zl[i >> 5];
    __syncthreads();
    const int o = tid;
    float wrow[32];
#pragma unroll
    for (int d = 0; d < 32; ++d) wrow[d] = wout[o * 256 + h * 32 + d];
    float m[32];
#pragma unroll 4
    for (int c = 0; c < 32; ++c) {
        float acc = 0.f;
#pragma unroll
        for (int d = 0; d < 32; ++d) acc += wrow[d] * cl[c * 32 + d];
        m[c] = acc;
    }
    unsigned* ph = (unsigned*)(mhi + (size_t)b * 65536 + o * 256 + h * 32);
    unsigned* pl = (unsigned*)(mlo + (size_t)b * 65536 + o * 256 + h * 32);
#pragma unroll
    for (int p = 0; p < 16; ++p) {
        unsigned hu, lu;
        split2(m[2 * p], m[2 * p + 1], hu, lu);
        ph[p] = hu; pl[p] = lu;
    }
}

// K_C: per 64-token tile: GEMM1 q (split-3 MFMA) -> qs fp32 LDS -> channel softmax
//      (in regs) -> packed bf16 q_s aliased into LDS -> GEMM2 (M hi/lo x q_hi) -> out
__launch_bounds__(256, 2)
__global__ void final_k(const float* __restrict__ x,
                        const unsigned short* __restrict__ whi,
                        const unsigned short* __restrict__ wlo,
                        const float* __restrict__ bqkv,
                        const unsigned short* __restrict__ mhi,
                        const unsigned short* __restrict__ mlo,
                        const float* __restrict__ bout, float* __restrict__ out)
{
    __shared__ float qs[16384];                 // 64 KB [ch 256][tok 64]
    unsigned short* qb = (unsigned short*)qs;   // aliased lower 32 KB after barrier
    const int tid  = threadIdx.x;
    const int wave = tid >> 6, lane = tid & 63;
    const int quad = lane >> 4, l16 = lane & 15;
    const int b = blockIdx.x >> 8, tile = blockIdx.x & 255;
    const int n0 = tile * 64;
    const float* xb = x + (size_t)b * 256 * NTOK;

    // ---- GEMM1: q[256][64] ----
    f32x4 acc[4][4];
#pragma unroll
    for (int rt = 0; rt < 4; ++rt)
#pragma unroll
        for (int ct = 0; ct < 4; ++ct) acc[rt][ct] = (f32x4){0.f, 0.f, 0.f, 0.f};

    for (int k0 = 0; k0 < 256; k0 += 32) {
        bf16x8 ah[4], al[4];
#pragma unroll
        for (int rt = 0; rt < 4; ++rt) {
            const int off = (wave * 64 + rt * 16 + l16) * 256 + k0 + quad * 8;
            ah[rt] = *(const bf16x8*)(whi + off);
            al[rt] = *(const bf16x8*)(wlo + off);
        }
        bf16x8 bh[4], bl[4];
#pragma unroll
        for (int ct = 0; ct < 4; ++ct) {
            const float* xp = xb + (size_t)(k0 + quad * 8) * NTOK + n0 + ct * 16 + l16;
            UB8 hu, lu;
#pragma unroll
            for (int p = 0; p < 4; ++p) {
                float v0 = xp[(2 * p) * NTOK];
                float v1 = xp[(2 * p + 1) * NTOK];
                split2(v0, v1, hu.u[p], lu.u[p]);
            }
            bh[ct] = hu.v; bl[ct] = lu.v;
        }
#pragma unroll
        for (int rt = 0; rt < 4; ++rt)
#pragma unroll
            for (int ct = 0; ct < 4; ++ct) {
                acc[rt][ct] = __builtin_amdgcn_mfma_f32_16x16x32_bf16(ah[rt], bh[ct], acc[rt][ct], 0, 0, 0);
                acc[rt][ct] = __builtin_amdgcn_mfma_f32_16x16x32_bf16(al[rt], bh[ct], acc[rt][ct], 0, 0, 0);
                acc[rt][ct] = __builtin_amdgcn_mfma_f32_16x16x32_bf16(ah[rt], bl[ct], acc[rt][ct], 0, 0, 0);
            }
    }
#pragma unroll
    for (int rt = 0; rt < 4; ++rt)
#pragma unroll
        for (int ct = 0; ct < 4; ++ct) {
            const int t = ct * 16 + l16;
#pragma unroll
            for (int r = 0; r < 4; ++r) {
                const int ch = wave * 64 + rt * 16 + quad * 4 + r;
                qs[ch * 64 + t] = acc[rt][ct][r] + bqkv[ch];
            }
        }
    __syncthreads();

    // ---- softmax over 32 channels per head, pack bf16 into regs ----
    unsigned qp[2][16];
#pragma unroll
    for (int rep = 0; rep < 2; ++rep) {
        const int h = (tid >> 6) + rep * 4;
        const int t = tid & 63;
        float e[32];
        float ssum = 0.f;
#pragma unroll
        for (int c = 0; c < 32; ++c) {
            e[c] = __expf(qs[(h * 32 + c) * 64 + t]);
            ssum += e[c];
        }
        const float rinv = 1.0f / ssum;
#pragma unroll
        for (int p = 0; p < 16; ++p) {
            unsigned u0 = (unsigned)bf16_trunc(e[2 * p] * rinv);
            unsigned u1 = (unsigned)bf16_trunc(e[2 * p + 1] * rinv);
            qp[rep][p] = u0 | (u1 << 16);
        }
    }
    __syncthreads();   // all qs reads complete before aliasing writes
#pragma unroll
    for (int rep = 0; rep < 2; ++rep) {
        const int h = (tid >> 6) + rep * 4;
        const int t = tid & 63;
        const int s = (t & 7) << 3;
#pragma unroll
        for (int g = 0; g < 4; ++g) {
            UB8 w8;
#pragma unroll
            for (int p = 0; p < 4; ++p) w8.u[p] = qp[rep][g * 4 + p];
            *(bf16x8*)&qb[t * 256 + ((h * 32 + g * 8) ^ s)] = w8.v;
        }
    }
    __syncthreads();

    // ---- GEMM2: out[256][64] = M (hi/lo) x q_s (hi) ----
#pragma unroll
    for (int rt = 0; rt < 4; ++rt)
#pragma unroll
        for (int ct = 0; ct < 4; ++ct) acc[rt][ct] = (f32x4){0.f, 0.f, 0.f, 0.f};
    const unsigned short* mhb = mhi + (size_t)b * 65536;
    const unsigned short* mlb = mlo + (size_t)b * 65536;

    for (int k0 = 0; k0 < 256; k0 += 32) {
        bf16x8 ah[4], al[4];
#pragma unroll
        for (int rt = 0; rt < 4; ++rt) {
            const int off = (wave * 64 + rt * 16 + l16) * 256 + k0 + quad * 8;
            ah[rt] = *(const bf16x8*)(mhb + off);
            al[rt] = *(const bf16x8*)(mlb + off);
        }
        bf16x8 bq[4];
#pragma unroll
        for (int ct = 0; ct < 4; ++ct) {
            const int t = ct * 16 + l16;
            const int s = (t & 7) << 3;
            bq[ct] = *(const bf16x8*)&qb[t * 256 + ((k0 + quad * 8) ^ s)];
        }
#pragma unroll
        for (int rt = 0; rt < 4; ++rt)
#pragma unroll
            for (int ct = 0; ct < 4; ++ct) {
                acc[rt][ct] = __builtin_amdgcn_mfma_f32_16x16x32_bf16(ah[rt], bq[ct], acc[rt][ct], 0, 0, 0);
                acc[rt][ct] = __builtin_amdgcn_mfma_f32_16x16x32_bf16(al[rt], bq[ct], acc[rt][ct], 0, 0, 0);
            }
    }

    float* ob = out + (size_t)b * 256 * NTOK;
#pragma unroll
    for (int rt = 0; rt < 4; ++rt)
#pragma unroll
        for (int ct = 0; ct < 4; ++ct) {
            const int t = ct * 16 + l16;
#pragma unroll
            for (int r = 0; r < 4; ++r) {
                const int o = wave * 64 + rt * 16 + quad * 4 + r;
                ob[(size_t)o * NTOK + n0 + t] = acc[rt][ct][r] + bout[o];
            }
        }
}

extern "C" void kernel_launch(void* const* d_in, const int* in_sizes, int n_in,
                              void* d_out, int out_size, void* d_ws, size_t ws_size,
                              hipStream_t stream)
{
    (void)in_sizes; (void)n_in; (void)out_size; (void)ws_size;
    const float* x    = (const float*)d_in[0];
    const float* wqkv = (const float*)d_in[1];
    const float* bqkv = (const float*)d_in[2];
    const float* wout = (const float*)d_in[3];
    const float* bout = (const float*)d_in[4];
    float* out = (float*)d_out;
    float* ws  = (float*)d_ws;

    unsigned short* whi = (unsigned short*)(ws + WHI_OFF);
    unsigned short* wlo = (unsigned short*)(ws + WLO_OFF);
    float*          ctx = ws + CTX_OFF;
    float*          zs  = ws + Z_OFF;
    unsigned short* mhi = (unsigned short*)(ws + MHI_OFF);
    unsigned short* mlo = (unsigned short*)(ws + MLO_OFF);

    hipMemsetAsync(ctx, 0, (65536 + 2048) * sizeof(float), stream);
    splitw_k<<<96, 256, 0, stream>>>(wqkv, whi, wlo);
    kv_ctx_k<<<512, 256, 0, stream>>>(x, whi, wlo, bqkv, ctx, zs);
    build_m_k<<<64, 256, 0, stream>>>(ctx, zs, wout, mhi, mlo);
    final_k<<<2048, 256, 0, stream>>>(x, whi, wlo, bqkv, mhi, mlo, bout, out);
}